// Round 1
// baseline (248.991 us; speedup 1.0000x reference)
//
#include <hip/hip_runtime.h>

// IntDVF: scaling-and-squaring integration of a stationary velocity field.
// ddf = dvf / 2^7; repeat 7x: ddf = ddf + trilerp(ddf, grid + ddf)
// Volume: (B=2, D=128, H=128, W=128, C=3) float32, coords clamped to [0,127].

#define NVOX (2 * 128 * 128 * 128)

__global__ __launch_bounds__(256) void intdvf_step(
    const float* __restrict__ src, float* __restrict__ dst,
    const float scale)
{
    const int idx = blockIdx.x * blockDim.x + threadIdx.x;
    if (idx >= NVOX) return;

    const int x = idx & 127;
    const int y = (idx >> 7) & 127;
    const int z = (idx >> 14) & 127;
    const int bbase = idx & ~((1 << 21) - 1);   // voxel index of this batch's start

    // center value of the (possibly pre-scale) field
    const float* p = src + (size_t)idx * 3;
    const float v0 = p[0] * scale;   // D (z) displacement
    const float v1 = p[1] * scale;   // H (y) displacement
    const float v2 = p[2] * scale;   // W (x) displacement

    // sample coords = grid + ddf, clamped (DeepReg resample behavior)
    const float cz = fminf(fmaxf((float)z + v0, 0.0f), 127.0f);
    const float cy = fminf(fmaxf((float)y + v1, 0.0f), 127.0f);
    const float cx = fminf(fmaxf((float)x + v2, 0.0f), 127.0f);

    const float fz = floorf(cz), fy = floorf(cy), fx = floorf(cx);
    const float wz = cz - fz,   wy = cy - fy,   wx = cx - fx;
    const int i0z = (int)fz, i0y = (int)fy, i0x = (int)fx;
    const int i1z = min(i0z + 1, 127);
    const int i1y = min(i0y + 1, 127);
    const int i1x = min(i0x + 1, 127);

    const float wz0 = 1.0f - wz, wy0 = 1.0f - wy, wx0 = 1.0f - wx;

    float o0 = 0.0f, o1 = 0.0f, o2 = 0.0f;
    #pragma unroll
    for (int b0 = 0; b0 < 2; ++b0) {
        const int   iz  = b0 ? i1z : i0z;
        const float wwz = b0 ? wz  : wz0;
        #pragma unroll
        for (int b1 = 0; b1 < 2; ++b1) {
            const int   iy   = b1 ? i1y : i0y;
            const float wwzy = wwz * (b1 ? wy : wy0);
            #pragma unroll
            for (int b2 = 0; b2 < 2; ++b2) {
                const int   ix = b2 ? i1x : i0x;
                const float wt = wwzy * (b2 ? wx : wx0);
                const float* q = src + (size_t)(bbase + ((iz << 14) | (iy << 7) | ix)) * 3;
                o0 += wt * q[0];
                o1 += wt * q[1];
                o2 += wt * q[2];
            }
        }
    }

    float* d = dst + (size_t)idx * 3;
    d[0] = v0 + o0 * scale;   // sampled volume is the scaled field too
    d[1] = v1 + o1 * scale;
    d[2] = v2 + o2 * scale;
}

extern "C" void kernel_launch(void* const* d_in, const int* in_sizes, int n_in,
                              void* d_out, int out_size, void* d_ws, size_t ws_size,
                              hipStream_t stream) {
    const float* dvf = (const float*)d_in[0];
    float* out = (float*)d_out;
    float* ws  = (float*)d_ws;

    const dim3 block(256);
    const dim3 grid((NVOX + 255) / 256);

    // 7 steps, ping-ponged so the final result lands in d_out.
    // Step 1 folds the /2^7 scaling into the reads.
    intdvf_step<<<grid, block, 0, stream>>>(dvf, out, 1.0f / 128.0f);
    intdvf_step<<<grid, block, 0, stream>>>(out, ws,  1.0f);
    intdvf_step<<<grid, block, 0, stream>>>(ws,  out, 1.0f);
    intdvf_step<<<grid, block, 0, stream>>>(out, ws,  1.0f);
    intdvf_step<<<grid, block, 0, stream>>>(ws,  out, 1.0f);
    intdvf_step<<<grid, block, 0, stream>>>(out, ws,  1.0f);
    intdvf_step<<<grid, block, 0, stream>>>(ws,  out, 1.0f);
}